// Round 14
// baseline (308.618 us; speedup 1.0000x reference)
//
#include <hip/hip_runtime.h>

#define NB 4
#define NC 3
#define BC 12
#define HW 65536
#define KCAP 32
#define MAXI 5
#define RUNCAP 16384
#define NSLOT 120     // 10 steps x 12 (b,c) slots
#define NCH 24        // chain slots: 2 passes x 12

typedef unsigned long long u64;
typedef unsigned int u32;

// ---------------- union-find (lock-free, link-to-MAX, path halving) ----------------
// root = MAX run index of the component -> root run holds the comp's max pixel.
__device__ __forceinline__ int uf_find(int* P, int x){
  while (true){
    int p = P[x];
    if (p == x) return x;
    int gp = P[p];
    if (gp == p) return p;
    P[x] = gp;   // path halving
    x = gp;
  }
}
__device__ __forceinline__ void uf_union_max(int* P, int a, int b){
  while (true){
    a = uf_find(P, a); b = uf_find(P, b);
    if (a == b) return;
    if (a > b){ int t = a; a = b; b = t; }   // a < b: link smaller root to larger
    int old = atomicCAS(&P[a], a, b);
    if (old == a) return;
    a = old;
  }
}

// walk runs of a 256-bit row (4 u64 words); emit(start, end_exclusive)
template<typename F>
__device__ __forceinline__ void walk_runs(const u64* wv, F&& emit){
  int open_s = -1;
  #pragma unroll
  for (int wi = 0; wi < 4; wi++){
    u64 v = wv[wi];
    int base = wi << 6;
    int pos = 0;
    while (pos < 64){
      u64 rem = v >> pos;
      if (open_s >= 0){
        u64 nz = ~rem;
        int z = nz ? __builtin_ctzll(nz) : 64;     // first zero at/after pos
        if (z >= 64 - pos){ pos = 64; }            // run continues past word
        else { emit(open_s, base + pos + z); open_s = -1; pos += z; }
      } else {
        if (rem == 0ull){ pos = 64; }
        else {
          int o = __builtin_ctzll(rem);            // first one
          open_s = base + pos + o;
          pos += o;
        }
      }
    }
  }
  if (open_s >= 0) emit(open_s, 256);
}

// ---------------- binarization: both base masks (pred -> g=0, tgt -> g=5) ----------------
__global__ void k_bin(const float* __restrict__ pred, const float* __restrict__ gum,
                      const int* __restrict__ tgt, u64* __restrict__ bmAll){
  int g = blockIdx.x * 256 + threadIdx.x;    // NB*HW threads
  int b = g >> 16, p = g & (HW - 1);
  size_t base = (size_t)b * NC * HW + p;
  float v0 = pred[base]        + gum[base];
  float v1 = pred[base + HW]   + gum[base + HW];
  float v2 = pred[base + 2*HW] + gum[base + 2*HW];
  int a = 0; float m = v0;
  if (v1 > m){ m = v1; a = 1; }
  if (v2 > m){ m = v2; a = 2; }
  int tg = tgt[(size_t)b * HW + p];
  u64 p0 = __ballot(a == 0), p1 = __ballot(a == 1), p2 = __ballot(a == 2);
  u64 t0 = __ballot(tg == 0), t1 = __ballot(tg == 1), t2 = __ballot(tg == 2);
  if ((threadIdx.x & 63) == 0){
    int w = p >> 6;
    int sp = b * NC;                       // pass0 base: step g=0
    bmAll[(size_t)(sp + 0) * 1024 + w] = p0;
    bmAll[(size_t)(sp + 1) * 1024 + w] = p1;
    bmAll[(size_t)(sp + 2) * 1024 + w] = p2;
    int st = 60 + b * NC;                  // pass1 base: step g=5
    bmAll[(size_t)(st + 0) * 1024 + w] = t0;
    bmAll[(size_t)(st + 1) * 1024 + w] = t1;
    bmAll[(size_t)(st + 2) * 1024 + w] = t2;
  }
}

// ---------------- 5x5 morphology on bitmaps: 4 independent jobs per launch ----------------
__global__ void k_morph4(const u64* __restrict__ bmAll, u64* __restrict__ bmAllW,
                         int4 srcs, int4 dsts, int4 flgs){
  int t = blockIdx.x * 256 + threadIdx.x;  // 4 * 12 * 1024 = 49152
  int job = t / 12288, rest = t % 12288;
  int s = rest >> 10, word = rest & 1023;
  int row = word >> 2, w = word & 3;
  int srcG = job == 0 ? srcs.x : job == 1 ? srcs.y : job == 2 ? srcs.z : srcs.w;
  int dstG = job == 0 ? dsts.x : job == 1 ? dsts.y : job == 2 ? dsts.z : dsts.w;
  int er   = job == 0 ? flgs.x : job == 1 ? flgs.y : job == 2 ? flgs.z : flgs.w;
  const u64* bs = bmAll + (size_t)(srcG * BC + s) * 1024;
  u64 res = er ? ~0ull : 0ull;
  for (int dy = -2; dy <= 2; dy++){
    int y = row + dy;
    if (y < 0 || y > 255){ if (er) res = 0; continue; }
    const u64* rw = bs + y * 4;
    u64 m = rw[w];
    u64 l = (w > 0) ? rw[w-1] : 0ull;
    u64 r = (w < 3) ? rw[w+1] : 0ull;
    u64 x1l = (m << 1) | (l >> 63);
    u64 x2l = (m << 2) | (l >> 62);
    u64 x1r = (m >> 1) | (r << 63);
    u64 x2r = (m >> 2) | (r << 62);
    u64 h = er ? (m & x1l & x2l & x1r & x2r) : (m | x1l | x2l | x1r | x2r);
    res = er ? (res & h) : (res | h);
  }
  bmAllW[(size_t)(dstG * BC + s) * 1024 + word] = res;
}

// ---------------- run-based CC in LDS, flag-segmented aggregation ----------------
// par: parent/root during CC; then size<<14|root (roots); then (lab<<14)|root (keys).
// pkz: run extents -> keyhi (roots) -> root->j map.
__global__ __launch_bounds__(1024) void k_cc_runs(
    const u64* __restrict__ bmAll, u32* __restrict__ selRuns,
    int* __restrict__ selCnt, float* __restrict__ sSel, float* __restrict__ scaleSel){
  __shared__ int par[RUNCAP];      // 64 KB
  __shared__ u32 pkz[RUNCAP];      // 64 KB
  __shared__ int rs[257];
  __shared__ u64 wcand[16*KCAP];   // 4 KB: per-wave top-32
  __shared__ u64 selKeys[KCAP];
  __shared__ int selRoot[KCAP];
  __shared__ int wsum[4], wsum2[4];
  __shared__ int lmS;
  int u = blockIdx.x, t = threadIdx.x;
  int lane = t & 63, wid = t >> 6;         // 16 waves
  bool rowT = t < 256;                     // thread t<256 owns row t
  u64 wv[4] = {0,0,0,0};
  int nr = 0;
  if (rowT){
    const u64* bp = bmAll + (size_t)u * 1024 + t * 4;
    #pragma unroll
    for (int i = 0; i < 4; i++) wv[i] = bp[i];
    walk_runs(wv, [&](int a, int b){ (void)a; (void)b; nr++; });
  }
  if (t == 0) lmS = 0;
  // scan #1: run-count offsets (rows live in waves 0..3); 2 barriers
  {
    int v = nr;
    #pragma unroll
    for (int d = 1; d < 64; d <<= 1){
      int o = __shfl_up(v, d);
      if (lane >= d) v += o;
    }
    if (rowT && lane == 63) wsum[wid] = v;
    __syncthreads();
    if (rowT){
      int pre = 0;
      for (int q = 0; q < wid; q++) pre += wsum[q];
      rs[t] = pre + v - nr;                // exclusive offset
      if (t == 255) rs[256] = pre + v;     // total
    }
    __syncthreads();
  }
  int NR = rs[256];
  int NRc = NR < RUNCAP ? NR : RUNCAP;
  int myBase = rowT ? rs[t] : 0;
  for (int i = t; i < NRc; i += 1024) par[i] = i;
  if (rowT){
    int o = myBase;
    walk_runs(wv, [&](int a, int b){
      if (o < RUNCAP) pkz[o] = ((u32)t << 16) | ((u32)a << 8) | (u32)(b - 1);
      o++;
    });
  }
  __syncthreads();
  // seam unions, one RUN per thread: binary search prev-row sorted run list.
  // overlap (8-conn) iff E1 >= s2-1 && s1 <= E2+1.
  for (int i = t; i < NRc; i += 1024){
    u32 v = pkz[i];
    int r = v >> 16;
    if (r == 0) continue;
    int s2 = (int)((v >> 8) & 255), E2 = (int)(v & 255);
    int a0 = rs[r-1], a1 = rs[r];
    if (a1 > NRc) a1 = NRc;
    if (a0 >= a1) continue;
    int lo = a0, hi = a1;
    while (lo < hi){
      int mid = (lo + hi) >> 1;
      if ((int)(pkz[mid] & 255) >= s2 - 1) hi = mid; else lo = mid + 1;
    }
    for (int j = lo; j < a1; j++){
      int s1 = (int)((pkz[j] >> 8) & 255);
      if (s1 > E2 + 1) break;
      uf_union_max(par, i, j);
    }
  }
  __syncthreads();
  // flatten (par entries are pure root indices after this barrier)
  for (int i = t; i < NRc; i += 1024){
    int r = i, p = par[r];
    while (p != r){ r = p; p = par[r]; }
    par[i] = r;
  }
  __syncthreads();
  // aggregate sizes into par[root] high bits via FLAG-SEGMENTED wave reduction:
  // one atomic per contiguous same-root lane segment (giant comps -> ~1 add/wave).
  // root read is masked (& 16383) because par[root] accumulates size concurrently.
  {
    int lm = 0;
    for (int i0 = 0; i0 < NRc; i0 += 1024){
      int i = i0 + t;
      int root = -1, len = 0;
      if (i < NRc){
        u32 v = pkz[i];
        int s0 = (int)((v >> 8) & 255), E = (int)(v & 255);
        len = E - s0 + 1;
        root = par[i] & 16383;
        lm = max(lm, (int)(v >> 16) * 256 + E);
      }
      int val = len;
      int prev = __shfl_up(root, 1);
      unsigned flg = (lane == 0 || prev != root) ? 1u : 0u;  // segment head
      #pragma unroll
      for (int d = 1; d < 64; d <<= 1){
        int ov = __shfl_up(val, d);
        unsigned of = __shfl_up(flg, d);
        if (lane >= d){
          if (!flg) val += ov;
          flg |= of;
        }
      }
      int nroot = __shfl_down(root, 1);
      bool last = (lane == 63) || (nroot != root);
      if (i < NRc && last) atomicAdd(&par[root], val << 14);
    }
    #pragma unroll
    for (int off = 32; off > 0; off >>= 1) lm = max(lm, __shfl_xor(lm, off));
    if (lane == 0) atomicMax(&lmS, lm);
  }
  __syncthreads();
  float maxLf = (float)(lmS >= 1 ? lmS : 1);
  // key conversion: roots get pkz=f32bits(size*lab) (>0), par=(lab<<14)|i.
  for (int i = t; i < NRc; i += 1024){
    int pv = par[i];
    if ((pv & 16383) == i){
      u32 v = pkz[i];
      int lab = (int)(v >> 16) * 256 + (int)(v & 255);
      if (lab > 0){
        float key = (float)((u32)pv >> 14) * (float)lab;
        pkz[i] = __float_as_uint(key);
        par[i] = (lab << 14) | i;
      } else {
        pkz[i] = 0;
      }
    }
  }
  __syncthreads();
  // per-wave top-32 tournament (no barriers): lane caches 1 best; winner's lane rescans.
  // u64 key: keyhi<<32 | (0xFFFF-lab)<<16 | runIdx(14b). Unique labels => total order.
  {
    u64 myBest = 0;
    for (int i = t; i < NRc; i += 1024){
      int pv = par[i];
      if ((pv & 16383) != i) continue;
      u32 kh = pkz[i];
      if (!kh) continue;
      u64 cand = ((u64)kh << 32) | ((u64)(0xFFFFu - ((u32)pv >> 14)) << 16) | (u64)i;
      if (cand > myBest) myBest = cand;
    }
    if (lane < KCAP) wcand[wid*KCAP + lane] = 0;
    for (int r = 0; r < KCAP; r++){
      u64 b = myBest;
      #pragma unroll
      for (int off = 32; off > 0; off >>= 1){
        u64 o = __shfl_xor(b, off);
        b = (o > b) ? o : b;
      }
      if (b == 0) break;
      if (lane == 0) wcand[wid*KCAP + r] = b;
      if (myBest == b){                      // only the owning lane
        pkz[(int)(b & 16383)] = 0;           // consume
        myBest = 0;
        for (int i = t; i < NRc; i += 1024){
          int pv = par[i];
          if ((pv & 16383) != i) continue;
          u32 kh = pkz[i];
          if (!kh) continue;
          u64 cand = ((u64)kh << 32) | ((u64)(0xFFFFu - ((u32)pv >> 14)) << 16) | (u64)i;
          if (cand > myBest) myBest = cand;
        }
      }
    }
  }
  __syncthreads();
  // wave 0 merges 16x32 candidates -> global top-32
  if (wid == 0){
    u64 c[8];
    #pragma unroll
    for (int q = 0; q < 8; q++) c[q] = wcand[q*64 + lane];
    if (lane < KCAP) selKeys[lane] = 0;
    for (int r = 0; r < KCAP; r++){
      u64 b = 0;
      #pragma unroll
      for (int q = 0; q < 8; q++) b = (c[q] > b) ? c[q] : b;
      #pragma unroll
      for (int off = 32; off > 0; off >>= 1){
        u64 o = __shfl_xor(b, off);
        b = (o > b) ? o : b;
      }
      if (b == 0) break;
      #pragma unroll
      for (int q = 0; q < 8; q++) if (c[q] == b) c[q] = 0;
      if (lane == 0) selKeys[r] = b;
    }
  }
  __syncthreads();
  // decode selections
  if (t < KCAP){
    u64 k = selKeys[t];
    if (k){
      int lab = 0xFFFF - (int)((k >> 16) & 0xFFFF);
      selRoot[t] = (int)(k & 0x3FFF);
      sSel[u*KCAP + t]     = __uint_as_float((u32)(k >> 32)) / maxLf;
      scaleSel[u*KCAP + t] = (float)lab / maxLf;
    } else {
      selRoot[t] = -1;
      sSel[u*KCAP + t] = 0.0f;
      scaleSel[u*KCAP + t] = 0.0f;
    }
  }
  __syncthreads();
  // pkz -> root->j map
  for (int i = t; i < NRc; i += 1024) pkz[i] = 255u;
  __syncthreads();
  if (t < KCAP && selRoot[t] >= 0) pkz[selRoot[t]] = (u32)t;
  __syncthreads();
  // count selected runs per row, scan #2 (2 barriers), then emit ordered selRuns
  int c = 0;
  if (rowT){
    int o = myBase;
    walk_runs(wv, [&](int a, int b){
      if (o < RUNCAP && pkz[par[o] & 16383] < KCAP) c++;
      o++;
    });
  }
  {
    int v = c;
    #pragma unroll
    for (int d = 1; d < 64; d <<= 1){
      int o = __shfl_up(v, d);
      if (lane >= d) v += o;
    }
    if (rowT && lane == 63) wsum2[wid] = v;
    __syncthreads();
    if (rowT){
      int pre = 0;
      for (int q = 0; q < wid; q++) pre += wsum2[q];
      int w = pre + v - c;
      size_t base = (size_t)u * RUNCAP;
      int o = myBase;
      walk_runs(wv, [&](int a, int b){
        if (o < RUNCAP){
          u32 j = pkz[par[o] & 16383];
          if (j < KCAP){
            selRuns[base + w] = (j << 24) | ((u32)t << 16) | ((u32)a << 8) | (u32)(b - 1);
            w++;
          }
        }
        o++;
      });
    }
    if (t == 0) selCnt[u] = wsum2[0] + wsum2[1] + wsum2[2] + wsum2[3];
  }
}

// ---------------- full matching chain: 5 steps, one block per (pass,slot) ----------------
// PbT layout: [slot][word(1024)][comp(32)] u64; per-wave cnt replication kills hot atomics.
__global__ __launch_bounds__(1024) void k_chainall(
    const u32* __restrict__ selRuns, const int* __restrict__ selCnt,
    const float* __restrict__ sSel, const float* __restrict__ scaleSel,
    float* __restrict__ barP, float* __restrict__ barT,
    int* __restrict__ n24, u64* __restrict__ PbT){
  int w = blockIdx.x, t = threadIdx.x;
  int pass = w / 12, s = w % 12;
  __shared__ int cnt[16*KCAP*KCAP];   // 64 KB: per-wave copies
  __shared__ float spL[KCAP];
  __shared__ int add_dst[KCAP];
  __shared__ int bestA[KCAP];
  __shared__ float bvA[KCAP];
  __shared__ int nS;
  if (t < KCAP) spL[t] = 0.0f;
  if (t == 0) nS = 0;
  float* bar = (pass ? barT : barP) + (size_t)s * KCAP * MAXI;
  u64* Pb = PbT + (size_t)w * KCAP * 1024;
  int g = t >> 5, k = t & 31;     // 32 groups x 32 lanes for OV
  int wid = t >> 6;               // wave id for cnt replication
  #pragma unroll 1
  for (int st = 0; st < 5; st++){
    int u = (pass * 5 + st) * BC + s;
    int tval = (st < 3) ? st + 2 : (st == 3 ? 1 : 0);   // schedule {2,3,4,1,0}
    for (int i = t; i < 16*KCAP*KCAP; i += 1024) cnt[i] = 0;
    __syncthreads();
    int n0 = nS;
    int NS = selCnt[u];
    const u32* rp = selRuns + (size_t)u * RUNCAP;
    // OV counts: group per run, lane per stored comp; per-wave cnt copy
    if (n0 > 0){
      for (int i = g; i < NS; i += 32){
        u32 v = rp[i];
        int j = v >> 24;
        int row = (v >> 16) & 255, s0 = (v >> 8) & 255, E = (int)(v & 255);
        int w0 = s0 >> 6, w1 = E >> 6;
        int acc = 0;
        if (k < n0){
          for (int wi = w0; wi <= w1; wi++){
            int lo = max(s0, wi << 6), hi = min(E + 1, (wi << 6) + 64);
            u64 mask = (hi - lo == 64) ? ~0ull : ((((u64)1 << (hi - lo)) - 1) << (lo - (wi << 6)));
            acc += __popcll(Pb[(size_t)(row * 4 + wi) * KCAP + k] & mask);
          }
          if (acc) atomicAdd(&cnt[wid*KCAP*KCAP + j*KCAP + k], acc);
        }
      }
    }
    __syncthreads();
    // fold 16 wave copies into copy 0 (each thread owns one (j,k) cell)
    {
      int tot = 0;
      #pragma unroll
      for (int wq = 0; wq < 16; wq++) tot += cnt[wq*KCAP*KCAP + t];
      cnt[t] = tot;
    }
    __syncthreads();
    // per-j argmax (entries k>=n0 are exactly 0; strict > keeps earliest index)
    if (t < KCAP){
      float sn = scaleSel[(size_t)u*KCAP + t];
      int best = 0; float bv = 0.0f;
      if (sn > 0.0f && n0 > 0){
        bv = sn * spL[0] * (float)cnt[t*KCAP + 0];
        for (int k2 = 1; k2 < n0; k2++){
          float ov = sn * spL[k2] * (float)cnt[t*KCAP + k2];
          if (ov > bv){ bv = ov; best = k2; }
        }
      }
      bestA[t] = best; bvA[t] = bv;
    }
    __syncthreads();
    // sequential decisions (mirrors lax.scan)
    if (t == 0){
      int n = n0;
      for (int j = 0; j < KCAP; j++){
        add_dst[j] = -1;
        float sv = scaleSel[(size_t)u*KCAP + j];
        if (sv <= 0.0f) continue;                    // invalid comp: no-op
        if (bvA[j] > 0.0f){                          // matched: overwrite stored slot
          bar[bestA[j]*MAXI + tval] = sSel[(size_t)u*KCAP + j];
        } else if (n < KCAP){                        // add new component
          bar[n*MAXI + tval] = sSel[(size_t)u*KCAP + j];
          spL[n] = sv;
          add_dst[j] = n;
          n++;
        }
      }
      nS = n;
    }
    __syncthreads();
    // zero PbT columns for added comps
    for (int j = 0; j < KCAP; j++){
      int d = add_dst[j];
      if (d < 0) continue;
      for (int x = t; x < 1024; x += 1024) Pb[(size_t)x * KCAP + d] = 0ull;
    }
    __syncthreads();
    // paint runs of added comps
    for (int i = t; i < NS; i += 1024){
      u32 v = rp[i];
      int j = v >> 24;
      int d = add_dst[j];
      if (d < 0) continue;
      int row = (v >> 16) & 255, s0 = (v >> 8) & 255, E = (int)(v & 255);
      int w0 = s0 >> 6, w1 = E >> 6;
      for (int wi = w0; wi <= w1; wi++){
        int lo = max(s0, wi << 6), hi = min(E + 1, (wi << 6) + 64);
        u64 mask = (hi - lo == 64) ? ~0ull : ((((u64)1 << (hi - lo)) - 1) << (lo - (wi << 6)));
        atomicOr(&Pb[(size_t)(row * 4 + wi) * KCAP + d], mask);
      }
    }
    __syncthreads();
  }
  if (t == 0) n24[w] = nS;
}

// ---------------- final loss (parallel: one thread per (s,k), LDS reduce) ----------------
__global__ void k_loss(const float* __restrict__ barP, const float* __restrict__ barT,
                       const int* __restrict__ n24, float* __restrict__ out){
  __shared__ float red[512];
  int t = threadIdx.x;
  float val = 0.0f;
  if (t < BC * KCAP){
    int s = t >> 5, k = t & 31;
    int np = n24[s], nt = n24[12 + s];
    if (k < np){
      const float* bp = barP + (size_t)(s*KCAP + k)*MAXI;
      float pmax = bp[0];
      #pragma unroll
      for (int q = 1; q < MAXI; q++) pmax = fmaxf(pmax, bp[q]);
      if (!(pmax > 0.0f)) pmax = 1.0f;
      float acc = 0.0f;
      #pragma unroll
      for (int q = 0; q < MAXI; q++){
        float tv = (k < nt) ? barT[(size_t)(s*KCAP + k)*MAXI + q] : 0.0f;
        float d = tv - bp[q];
        acc += d * d;
      }
      val = acc / (pmax * pmax);
    }
  }
  red[t] = val;
  __syncthreads();
  for (int off = 256; off > 0; off >>= 1){
    if (t < off) red[t] += red[t + off];
    __syncthreads();
  }
  if (t == 0) out[0] = red[0] * 0.25f;   // mean over B=4
}

extern "C" void kernel_launch(void* const* d_in, const int* in_sizes, int n_in,
                              void* d_out, int out_size, void* d_ws, size_t ws_size,
                              hipStream_t stream){
  const float* pred = (const float*)d_in[0];
  const float* gum  = (const float*)d_in[1];
  const int*   tgt  = (const int*)d_in[2];
  float* out = (float*)d_out;
  char* ws = (char*)d_ws;
  size_t off = 0;
  auto alloc = [&](size_t bytes)->char*{
    char* p = ws + off;
    off += (bytes + 255) & ~(size_t)255;
    return p;
  };
  u64* bmAll   = (u64*)alloc((size_t)NSLOT*1024*8);         // 0.98 MB
  u32* selRuns = (u32*)alloc((size_t)NSLOT*RUNCAP*4);       // 7.9 MB
  int* selCnt  = (int*)alloc(NSLOT*4);
  float* sSel     = (float*)alloc((size_t)NSLOT*KCAP*4);
  float* scaleSel = (float*)alloc((size_t)NSLOT*KCAP*4);
  u64* PbT     = (u64*)alloc((size_t)NCH*KCAP*1024*8);      // 6.3 MB, [slot][word][comp]
  int* n24     = (int*)alloc(NCH*4);
  // zero region: barP | barT
  size_t zbytes = (size_t)(BC*KCAP*MAXI*2)*4;
  char* zreg = alloc(zbytes);
  float* barP = (float*)zreg;
  float* barT = barP + BC*KCAP*MAXI;
  if (off > ws_size) return;

  hipMemsetAsync(zreg, 0, zbytes, stream);
  // binarize both passes' base masks (steps g=0 and g=5)
  k_bin<<<(NB*HW)/256,256,0,stream>>>(pred, gum, tgt, bmAll);
  // morphology: e1/d1 from base, then e2/d2, both passes batched
  k_morph4<<<192,256,0,stream>>>(bmAll, bmAll, make_int4(0,0,5,5), make_int4(1,3,6,8), make_int4(1,0,1,0));
  k_morph4<<<192,256,0,stream>>>(bmAll, bmAll, make_int4(1,3,6,8), make_int4(2,4,7,9), make_int4(1,0,1,0));
  // run-based CC + selection over all 120 slots
  k_cc_runs<<<NSLOT,1024,0,stream>>>(bmAll, selRuns, selCnt, sSel, scaleSel);
  // full matching chain (5 steps internal), 24 independent blocks
  k_chainall<<<NCH,1024,0,stream>>>(selRuns, selCnt, sSel, scaleSel, barP, barT, n24, PbT);
  k_loss<<<1,512,0,stream>>>(barP, barT, n24, out);
}

// Round 15
// 270.984 us; speedup vs baseline: 1.1389x; 1.1389x over previous
//
#include <hip/hip_runtime.h>

#define NB 4
#define NC 3
#define BC 12
#define HW 65536
#define KCAP 32
#define MAXI 5
#define RUNCAP 16384
#define NSLOT 120     // 10 steps x 12 (b,c) slots
#define NCH 24        // chain slots: 2 passes x 12

typedef unsigned long long u64;
typedef unsigned int u32;

// ---------------- union-find (lock-free, link-to-MAX, path halving) ----------------
__device__ __forceinline__ int uf_find(int* P, int x){
  while (true){
    int p = P[x];
    if (p == x) return x;
    int gp = P[p];
    if (gp == p) return p;
    P[x] = gp;   // path halving
    x = gp;
  }
}
__device__ __forceinline__ void uf_union_max(int* P, int a, int b){
  while (true){
    a = uf_find(P, a); b = uf_find(P, b);
    if (a == b) return;
    if (a > b){ int t = a; a = b; b = t; }   // a < b: link smaller root to larger
    int old = atomicCAS(&P[a], a, b);
    if (old == a) return;
    a = old;
  }
}

// walk runs of a 256-bit row (4 u64 words); emit(start, end_exclusive)
template<typename F>
__device__ __forceinline__ void walk_runs(const u64* wv, F&& emit){
  int open_s = -1;
  #pragma unroll
  for (int wi = 0; wi < 4; wi++){
    u64 v = wv[wi];
    int base = wi << 6;
    int pos = 0;
    while (pos < 64){
      u64 rem = v >> pos;
      if (open_s >= 0){
        u64 nz = ~rem;
        int z = nz ? __builtin_ctzll(nz) : 64;     // first zero at/after pos
        if (z >= 64 - pos){ pos = 64; }            // run continues past word
        else { emit(open_s, base + pos + z); open_s = -1; pos += z; }
      } else {
        if (rem == 0ull){ pos = 64; }
        else {
          int o = __builtin_ctzll(rem);            // first one
          open_s = base + pos + o;
          pos += o;
        }
      }
    }
  }
  if (open_s >= 0) emit(open_s, 256);
}

// ---------------- binarization: both base masks (pred -> g=0, tgt -> g=5) ----------------
__global__ void k_bin(const float* __restrict__ pred, const float* __restrict__ gum,
                      const int* __restrict__ tgt, u64* __restrict__ bmAll){
  int g = blockIdx.x * 256 + threadIdx.x;    // NB*HW threads
  int b = g >> 16, p = g & (HW - 1);
  size_t base = (size_t)b * NC * HW + p;
  float v0 = pred[base]        + gum[base];
  float v1 = pred[base + HW]   + gum[base + HW];
  float v2 = pred[base + 2*HW] + gum[base + 2*HW];
  int a = 0; float m = v0;
  if (v1 > m){ m = v1; a = 1; }
  if (v2 > m){ m = v2; a = 2; }
  int tg = tgt[(size_t)b * HW + p];
  u64 p0 = __ballot(a == 0), p1 = __ballot(a == 1), p2 = __ballot(a == 2);
  u64 t0 = __ballot(tg == 0), t1 = __ballot(tg == 1), t2 = __ballot(tg == 2);
  if ((threadIdx.x & 63) == 0){
    int w = p >> 6;
    int sp = b * NC;                       // pass0 base: step g=0
    bmAll[(size_t)(sp + 0) * 1024 + w] = p0;
    bmAll[(size_t)(sp + 1) * 1024 + w] = p1;
    bmAll[(size_t)(sp + 2) * 1024 + w] = p2;
    int st = 60 + b * NC;                  // pass1 base: step g=5
    bmAll[(size_t)(st + 0) * 1024 + w] = t0;
    bmAll[(size_t)(st + 1) * 1024 + w] = t1;
    bmAll[(size_t)(st + 2) * 1024 + w] = t2;
  }
}

// ---------------- 5x5 morphology on bitmaps: 4 independent jobs per launch ----------------
__global__ void k_morph4(const u64* __restrict__ bmAll, u64* __restrict__ bmAllW,
                         int4 srcs, int4 dsts, int4 flgs){
  int t = blockIdx.x * 256 + threadIdx.x;  // 4 * 12 * 1024 = 49152
  int job = t / 12288, rest = t % 12288;
  int s = rest >> 10, word = rest & 1023;
  int row = word >> 2, w = word & 3;
  int srcG = job == 0 ? srcs.x : job == 1 ? srcs.y : job == 2 ? srcs.z : srcs.w;
  int dstG = job == 0 ? dsts.x : job == 1 ? dsts.y : job == 2 ? dsts.z : dsts.w;
  int er   = job == 0 ? flgs.x : job == 1 ? flgs.y : job == 2 ? flgs.z : flgs.w;
  const u64* bs = bmAll + (size_t)(srcG * BC + s) * 1024;
  u64 res = er ? ~0ull : 0ull;
  for (int dy = -2; dy <= 2; dy++){
    int y = row + dy;
    if (y < 0 || y > 255){ if (er) res = 0; continue; }
    const u64* rw = bs + y * 4;
    u64 m = rw[w];
    u64 l = (w > 0) ? rw[w-1] : 0ull;
    u64 r = (w < 3) ? rw[w+1] : 0ull;
    u64 x1l = (m << 1) | (l >> 63);
    u64 x2l = (m << 2) | (l >> 62);
    u64 x1r = (m >> 1) | (r << 63);
    u64 x2r = (m >> 2) | (r << 62);
    u64 h = er ? (m & x1l & x2l & x1r & x2r) : (m | x1l | x2l | x1r | x2r);
    res = er ? (res & h) : (res | h);
  }
  bmAllW[(size_t)(dstG * BC + s) * 1024 + word] = res;
}

// ---------------- run-based CC in LDS, flag-segmented aggregation (r14, passing) ----------
__global__ __launch_bounds__(1024) void k_cc_runs(
    const u64* __restrict__ bmAll, u32* __restrict__ selRuns,
    int* __restrict__ selCnt, float* __restrict__ sSel, float* __restrict__ scaleSel){
  __shared__ int par[RUNCAP];      // 64 KB
  __shared__ u32 pkz[RUNCAP];      // 64 KB
  __shared__ int rs[257];
  __shared__ u64 wcand[16*KCAP];   // 4 KB: per-wave top-32
  __shared__ u64 selKeys[KCAP];
  __shared__ int selRoot[KCAP];
  __shared__ int wsum[4], wsum2[4];
  __shared__ int lmS;
  int u = blockIdx.x, t = threadIdx.x;
  int lane = t & 63, wid = t >> 6;         // 16 waves
  bool rowT = t < 256;                     // thread t<256 owns row t
  u64 wv[4] = {0,0,0,0};
  int nr = 0;
  if (rowT){
    const u64* bp = bmAll + (size_t)u * 1024 + t * 4;
    #pragma unroll
    for (int i = 0; i < 4; i++) wv[i] = bp[i];
    walk_runs(wv, [&](int a, int b){ (void)a; (void)b; nr++; });
  }
  if (t == 0) lmS = 0;
  // scan #1: run-count offsets
  {
    int v = nr;
    #pragma unroll
    for (int d = 1; d < 64; d <<= 1){
      int o = __shfl_up(v, d);
      if (lane >= d) v += o;
    }
    if (rowT && lane == 63) wsum[wid] = v;
    __syncthreads();
    if (rowT){
      int pre = 0;
      for (int q = 0; q < wid; q++) pre += wsum[q];
      rs[t] = pre + v - nr;                // exclusive offset
      if (t == 255) rs[256] = pre + v;     // total
    }
    __syncthreads();
  }
  int NR = rs[256];
  int NRc = NR < RUNCAP ? NR : RUNCAP;
  int myBase = rowT ? rs[t] : 0;
  for (int i = t; i < NRc; i += 1024) par[i] = i;
  if (rowT){
    int o = myBase;
    walk_runs(wv, [&](int a, int b){
      if (o < RUNCAP) pkz[o] = ((u32)t << 16) | ((u32)a << 8) | (u32)(b - 1);
      o++;
    });
  }
  __syncthreads();
  // seam unions: binary search prev-row sorted run list; overlap iff E1>=s2-1 && s1<=E2+1
  for (int i = t; i < NRc; i += 1024){
    u32 v = pkz[i];
    int r = v >> 16;
    if (r == 0) continue;
    int s2 = (int)((v >> 8) & 255), E2 = (int)(v & 255);
    int a0 = rs[r-1], a1 = rs[r];
    if (a1 > NRc) a1 = NRc;
    if (a0 >= a1) continue;
    int lo = a0, hi = a1;
    while (lo < hi){
      int mid = (lo + hi) >> 1;
      if ((int)(pkz[mid] & 255) >= s2 - 1) hi = mid; else lo = mid + 1;
    }
    for (int j = lo; j < a1; j++){
      int s1 = (int)((pkz[j] >> 8) & 255);
      if (s1 > E2 + 1) break;
      uf_union_max(par, i, j);
    }
  }
  __syncthreads();
  // flatten
  for (int i = t; i < NRc; i += 1024){
    int r = i, p = par[r];
    while (p != r){ r = p; p = par[r]; }
    par[i] = r;
  }
  __syncthreads();
  // flag-segmented wave aggregation of sizes into par[root] high bits
  {
    int lm = 0;
    for (int i0 = 0; i0 < NRc; i0 += 1024){
      int i = i0 + t;
      int root = -1, len = 0;
      if (i < NRc){
        u32 v = pkz[i];
        int s0 = (int)((v >> 8) & 255), E = (int)(v & 255);
        len = E - s0 + 1;
        root = par[i] & 16383;
        lm = max(lm, (int)(v >> 16) * 256 + E);
      }
      int val = len;
      int prev = __shfl_up(root, 1);
      unsigned flg = (lane == 0 || prev != root) ? 1u : 0u;  // segment head
      #pragma unroll
      for (int d = 1; d < 64; d <<= 1){
        int ov = __shfl_up(val, d);
        unsigned of = __shfl_up(flg, d);
        if (lane >= d){
          if (!flg) val += ov;
          flg |= of;
        }
      }
      int nroot = __shfl_down(root, 1);
      bool last = (lane == 63) || (nroot != root);
      if (i < NRc && last) atomicAdd(&par[root], val << 14);
    }
    #pragma unroll
    for (int off = 32; off > 0; off >>= 1) lm = max(lm, __shfl_xor(lm, off));
    if (lane == 0) atomicMax(&lmS, lm);
  }
  __syncthreads();
  float maxLf = (float)(lmS >= 1 ? lmS : 1);
  // key conversion: roots get pkz=f32bits(size*lab) (>0), par=(lab<<14)|i.
  for (int i = t; i < NRc; i += 1024){
    int pv = par[i];
    if ((pv & 16383) == i){
      u32 v = pkz[i];
      int lab = (int)(v >> 16) * 256 + (int)(v & 255);
      if (lab > 0){
        float key = (float)((u32)pv >> 14) * (float)lab;
        pkz[i] = __float_as_uint(key);
        par[i] = (lab << 14) | i;
      } else {
        pkz[i] = 0;
      }
    }
  }
  __syncthreads();
  // per-wave top-32 tournament; u64 key keyhi<<32 | (0xFFFF-lab)<<16 | runIdx
  {
    u64 myBest = 0;
    for (int i = t; i < NRc; i += 1024){
      int pv = par[i];
      if ((pv & 16383) != i) continue;
      u32 kh = pkz[i];
      if (!kh) continue;
      u64 cand = ((u64)kh << 32) | ((u64)(0xFFFFu - ((u32)pv >> 14)) << 16) | (u64)i;
      if (cand > myBest) myBest = cand;
    }
    if (lane < KCAP) wcand[wid*KCAP + lane] = 0;
    for (int r = 0; r < KCAP; r++){
      u64 b = myBest;
      #pragma unroll
      for (int off = 32; off > 0; off >>= 1){
        u64 o = __shfl_xor(b, off);
        b = (o > b) ? o : b;
      }
      if (b == 0) break;
      if (lane == 0) wcand[wid*KCAP + r] = b;
      if (myBest == b){                      // only the owning lane
        pkz[(int)(b & 16383)] = 0;           // consume
        myBest = 0;
        for (int i = t; i < NRc; i += 1024){
          int pv = par[i];
          if ((pv & 16383) != i) continue;
          u32 kh = pkz[i];
          if (!kh) continue;
          u64 cand = ((u64)kh << 32) | ((u64)(0xFFFFu - ((u32)pv >> 14)) << 16) | (u64)i;
          if (cand > myBest) myBest = cand;
        }
      }
    }
  }
  __syncthreads();
  // wave 0 merges 16x32 candidates -> global top-32
  if (wid == 0){
    u64 c[8];
    #pragma unroll
    for (int q = 0; q < 8; q++) c[q] = wcand[q*64 + lane];
    if (lane < KCAP) selKeys[lane] = 0;
    for (int r = 0; r < KCAP; r++){
      u64 b = 0;
      #pragma unroll
      for (int q = 0; q < 8; q++) b = (c[q] > b) ? c[q] : b;
      #pragma unroll
      for (int off = 32; off > 0; off >>= 1){
        u64 o = __shfl_xor(b, off);
        b = (o > b) ? o : b;
      }
      if (b == 0) break;
      #pragma unroll
      for (int q = 0; q < 8; q++) if (c[q] == b) c[q] = 0;
      if (lane == 0) selKeys[r] = b;
    }
  }
  __syncthreads();
  // decode selections
  if (t < KCAP){
    u64 k = selKeys[t];
    if (k){
      int lab = 0xFFFF - (int)((k >> 16) & 0xFFFF);
      selRoot[t] = (int)(k & 0x3FFF);
      sSel[u*KCAP + t]     = __uint_as_float((u32)(k >> 32)) / maxLf;
      scaleSel[u*KCAP + t] = (float)lab / maxLf;
    } else {
      selRoot[t] = -1;
      sSel[u*KCAP + t] = 0.0f;
      scaleSel[u*KCAP + t] = 0.0f;
    }
  }
  __syncthreads();
  // pkz -> root->j map
  for (int i = t; i < NRc; i += 1024) pkz[i] = 255u;
  __syncthreads();
  if (t < KCAP && selRoot[t] >= 0) pkz[selRoot[t]] = (u32)t;
  __syncthreads();
  // count selected runs per row, scan #2, then emit ordered selRuns
  int c = 0;
  if (rowT){
    int o = myBase;
    walk_runs(wv, [&](int a, int b){
      if (o < RUNCAP && pkz[par[o] & 16383] < KCAP) c++;
      o++;
    });
  }
  {
    int v = c;
    #pragma unroll
    for (int d = 1; d < 64; d <<= 1){
      int o = __shfl_up(v, d);
      if (lane >= d) v += o;
    }
    if (rowT && lane == 63) wsum2[wid] = v;
    __syncthreads();
    if (rowT){
      int pre = 0;
      for (int q = 0; q < wid; q++) pre += wsum2[q];
      int w = pre + v - c;
      size_t base = (size_t)u * RUNCAP;
      int o = myBase;
      walk_runs(wv, [&](int a, int b){
        if (o < RUNCAP){
          u32 j = pkz[par[o] & 16383];
          if (j < KCAP){
            selRuns[base + w] = (j << 24) | ((u32)t << 16) | ((u32)a << 8) | (u32)(b - 1);
            w++;
          }
        }
        o++;
      });
    }
    if (t == 0) selCnt[u] = wsum2[0] + wsum2[1] + wsum2[2] + wsum2[3];
  }
}

// ---------------- full matching chain: 5 steps, one block per (pass,slot) ----------------
// PbT: [slot][word(1024)][comp(32)] u64. OV: 4-run ILP; paint: batched LDS colbuf.
__global__ __launch_bounds__(1024, 4) void k_chainall(
    const u32* __restrict__ selRuns, const int* __restrict__ selCnt,
    const float* __restrict__ sSel, const float* __restrict__ scaleSel,
    float* __restrict__ barP, float* __restrict__ barT,
    int* __restrict__ n24, u64* __restrict__ PbT){
  int w = blockIdx.x, t = threadIdx.x;
  int pass = w / 12, s = w % 12;
  __shared__ u64 shbuf[8192];         // 64 KB: cnt copies (int alias) / paint colbuf (u64)
  __shared__ float spL[KCAP];
  __shared__ int add_dst[KCAP];
  __shared__ int bestA[KCAP];
  __shared__ float bvA[KCAP];
  __shared__ int nS;
  int* cnt = (int*)shbuf;             // 16 copies x KCAP*KCAP ints = 64 KB
  if (t < KCAP) spL[t] = 0.0f;
  if (t == 0) nS = 0;
  float* bar = (pass ? barT : barP) + (size_t)s * KCAP * MAXI;
  u64* Pb = PbT + (size_t)w * KCAP * 1024;
  int g = t >> 5, k = t & 31;     // 32 groups x 32 lanes for OV
  int wid = t >> 6;               // wave id for cnt replication
  int cw = wid * KCAP * KCAP;
  #pragma unroll 1
  for (int st = 0; st < 5; st++){
    int u = (pass * 5 + st) * BC + s;
    int tval = (st < 3) ? st + 2 : (st == 3 ? 1 : 0);   // schedule {2,3,4,1,0}
    for (int i = t; i < 16*KCAP*KCAP; i += 1024) cnt[i] = 0;
    __syncthreads();
    int n0 = nS;
    int NS = selCnt[u];
    const u32* rp = selRuns + (size_t)u * RUNCAP;
    // OV counts: group per run, lane per stored comp; 4 independent run-chains per iter
    #define OVRUN(vv, jj, aacc) { \
      jj = (int)((vv) >> 24); aacc = 0; \
      if (jj < KCAP && k < n0){ \
        int row_ = ((vv) >> 16) & 255, s0_ = ((vv) >> 8) & 255, E_ = (int)((vv) & 255); \
        int w0_ = s0_ >> 6, w1_ = E_ >> 6; \
        for (int wi_ = w0_; wi_ <= w1_; wi_++){ \
          int lo_ = max(s0_, wi_ << 6), hi_ = min(E_ + 1, (wi_ << 6) + 64); \
          u64 m_ = (hi_ - lo_ == 64) ? ~0ull : ((((u64)1 << (hi_ - lo_)) - 1) << (lo_ - (wi_ << 6))); \
          aacc += __popcll(Pb[(size_t)(row_ * 4 + wi_) * KCAP + k] & m_); \
        } \
      } }
    if (n0 > 0){
      for (int i = g; i < NS; i += 128){
        u32 va = rp[i];
        u32 vb = (i + 32 < NS) ? rp[i + 32] : 0xFFFFFFFFu;
        u32 vc = (i + 64 < NS) ? rp[i + 64] : 0xFFFFFFFFu;
        u32 vd = (i + 96 < NS) ? rp[i + 96] : 0xFFFFFFFFu;
        int j0, j1, j2, j3, a0, a1, a2, a3;
        OVRUN(va, j0, a0);
        OVRUN(vb, j1, a1);
        OVRUN(vc, j2, a2);
        OVRUN(vd, j3, a3);
        if (a0) atomicAdd(&cnt[cw + j0*KCAP + k], a0);
        if (a1) atomicAdd(&cnt[cw + j1*KCAP + k], a1);
        if (a2) atomicAdd(&cnt[cw + j2*KCAP + k], a2);
        if (a3) atomicAdd(&cnt[cw + j3*KCAP + k], a3);
      }
    }
    #undef OVRUN
    __syncthreads();
    // fold 16 wave copies into copy 0 (each thread owns one (j,k) cell)
    {
      int tot = 0;
      #pragma unroll
      for (int wq = 0; wq < 16; wq++) tot += cnt[wq*KCAP*KCAP + t];
      __syncthreads();
      cnt[t] = tot;
    }
    __syncthreads();
    // per-j argmax (entries k>=n0 are exactly 0; strict > keeps earliest index)
    if (t < KCAP){
      float sn = scaleSel[(size_t)u*KCAP + t];
      int best = 0; float bv = 0.0f;
      if (sn > 0.0f && n0 > 0){
        bv = sn * spL[0] * (float)cnt[t*KCAP + 0];
        for (int k2 = 1; k2 < n0; k2++){
          float ov = sn * spL[k2] * (float)cnt[t*KCAP + k2];
          if (ov > bv){ bv = ov; best = k2; }
        }
      }
      bestA[t] = best; bvA[t] = bv;
    }
    __syncthreads();
    // sequential decisions (mirrors lax.scan)
    if (t == 0){
      int n = n0;
      for (int j = 0; j < KCAP; j++){
        add_dst[j] = -1;
        float sv = scaleSel[(size_t)u*KCAP + j];
        if (sv <= 0.0f) continue;                    // invalid comp: no-op
        if (bvA[j] > 0.0f){                          // matched: overwrite stored slot
          bar[bestA[j]*MAXI + tval] = sSel[(size_t)u*KCAP + j];
        } else if (n < KCAP){                        // add new component
          bar[n*MAXI + tval] = sSel[(size_t)u*KCAP + j];
          spL[n] = sv;
          add_dst[j] = n;
          n++;
        }
      }
      nS = n;
    }
    __syncthreads();
    int nTot = nS;
    // batched paint: build up to 8 added columns in LDS, then coalesced column writes
    for (int b0 = n0; b0 < nTot; b0 += 8){
      int bcnt = min(8, nTot - b0);
      for (int x = t; x < 8192; x += 1024) shbuf[x] = 0ull;
      __syncthreads();
      for (int i = t; i < NS; i += 1024){
        u32 v = rp[i];
        int j = v >> 24;
        if (j >= KCAP) continue;
        int d = add_dst[j];
        if (d < b0 || d >= b0 + bcnt) continue;
        int row = (v >> 16) & 255, s0 = (v >> 8) & 255, E = (int)(v & 255);
        int w0 = s0 >> 6, w1 = E >> 6;
        for (int wi = w0; wi <= w1; wi++){
          int lo = max(s0, wi << 6), hi = min(E + 1, (wi << 6) + 64);
          u64 mask = (hi - lo == 64) ? ~0ull : ((((u64)1 << (hi - lo)) - 1) << (lo - (wi << 6)));
          atomicOr(&shbuf[(size_t)(row * 4 + wi) * 8 + (d - b0)], mask);
        }
      }
      __syncthreads();
      // write out: thread x writes comps b0..b0+bcnt of word x (contiguous u64s)
      for (int dd = 0; dd < bcnt; dd++)
        Pb[(size_t)t * KCAP + b0 + dd] = shbuf[(size_t)t * 8 + dd];
      __syncthreads();
    }
    __syncthreads();
  }
  if (t == 0) n24[w] = nS;
}

// ---------------- final loss (parallel: one thread per (s,k), LDS reduce) ----------------
__global__ void k_loss(const float* __restrict__ barP, const float* __restrict__ barT,
                       const int* __restrict__ n24, float* __restrict__ out){
  __shared__ float red[512];
  int t = threadIdx.x;
  float val = 0.0f;
  if (t < BC * KCAP){
    int s = t >> 5, k = t & 31;
    int np = n24[s], nt = n24[12 + s];
    if (k < np){
      const float* bp = barP + (size_t)(s*KCAP + k)*MAXI;
      float pmax = bp[0];
      #pragma unroll
      for (int q = 1; q < MAXI; q++) pmax = fmaxf(pmax, bp[q]);
      if (!(pmax > 0.0f)) pmax = 1.0f;
      float acc = 0.0f;
      #pragma unroll
      for (int q = 0; q < MAXI; q++){
        float tv = (k < nt) ? barT[(size_t)(s*KCAP + k)*MAXI + q] : 0.0f;
        float d = tv - bp[q];
        acc += d * d;
      }
      val = acc / (pmax * pmax);
    }
  }
  red[t] = val;
  __syncthreads();
  for (int off = 256; off > 0; off >>= 1){
    if (t < off) red[t] += red[t + off];
    __syncthreads();
  }
  if (t == 0) out[0] = red[0] * 0.25f;   // mean over B=4
}

extern "C" void kernel_launch(void* const* d_in, const int* in_sizes, int n_in,
                              void* d_out, int out_size, void* d_ws, size_t ws_size,
                              hipStream_t stream){
  const float* pred = (const float*)d_in[0];
  const float* gum  = (const float*)d_in[1];
  const int*   tgt  = (const int*)d_in[2];
  float* out = (float*)d_out;
  char* ws = (char*)d_ws;
  size_t off = 0;
  auto alloc = [&](size_t bytes)->char*{
    char* p = ws + off;
    off += (bytes + 255) & ~(size_t)255;
    return p;
  };
  u64* bmAll   = (u64*)alloc((size_t)NSLOT*1024*8);         // 0.98 MB
  u32* selRuns = (u32*)alloc((size_t)NSLOT*RUNCAP*4);       // 7.9 MB
  int* selCnt  = (int*)alloc(NSLOT*4);
  float* sSel     = (float*)alloc((size_t)NSLOT*KCAP*4);
  float* scaleSel = (float*)alloc((size_t)NSLOT*KCAP*4);
  u64* PbT     = (u64*)alloc((size_t)NCH*KCAP*1024*8);      // 6.3 MB, [slot][word][comp]
  int* n24     = (int*)alloc(NCH*4);
  // zero region: barP | barT
  size_t zbytes = (size_t)(BC*KCAP*MAXI*2)*4;
  char* zreg = alloc(zbytes);
  float* barP = (float*)zreg;
  float* barT = barP + BC*KCAP*MAXI;
  if (off > ws_size) return;

  hipMemsetAsync(zreg, 0, zbytes, stream);
  // binarize both passes' base masks (steps g=0 and g=5)
  k_bin<<<(NB*HW)/256,256,0,stream>>>(pred, gum, tgt, bmAll);
  // morphology: e1/d1 from base, then e2/d2, both passes batched
  k_morph4<<<192,256,0,stream>>>(bmAll, bmAll, make_int4(0,0,5,5), make_int4(1,3,6,8), make_int4(1,0,1,0));
  k_morph4<<<192,256,0,stream>>>(bmAll, bmAll, make_int4(1,3,6,8), make_int4(2,4,7,9), make_int4(1,0,1,0));
  // run-based CC + selection over all 120 slots
  k_cc_runs<<<NSLOT,1024,0,stream>>>(bmAll, selRuns, selCnt, sSel, scaleSel);
  // full matching chain (5 steps internal), 24 independent blocks
  k_chainall<<<NCH,1024,0,stream>>>(selRuns, selCnt, sSel, scaleSel, barP, barT, n24, PbT);
  k_loss<<<1,512,0,stream>>>(barP, barT, n24, out);
}